// Round 1
// baseline (378.291 us; speedup 1.0000x reference)
//
#include <hip/hip_runtime.h>
#include <hip/hip_bf16.h>
#include <stdint.h>

// Problem constants (B, L, QD, H, D) = (2, 2048, 1024, 16, 64)
#define BB 2
#define LL 2048
#define QDIM 1024
#define NH 16
#define HD 64
// qkv row layout: [q(16*64) | k(16*64) | v(16*64)] = 3072 bf16 per (b,l)

using bf16x8 = __attribute__((ext_vector_type(8))) __bf16;
using f32x4  = __attribute__((ext_vector_type(4))) float;
using u16x8  = __attribute__((ext_vector_type(8))) unsigned short;

__device__ __forceinline__ unsigned short f2bf(float f) {
  uint32_t u = __builtin_bit_cast(uint32_t, f);
  u = (u + 0x7fffu + ((u >> 16) & 1u)) >> 16;   // RNE
  return (unsigned short)u;
}
__device__ __forceinline__ float bf2f(unsigned short h) {
  uint32_t u = ((uint32_t)h) << 16;
  return __builtin_bit_cast(float, u);
}

__device__ __forceinline__ void gload_lds16(const void* g, void* l) {
  __builtin_amdgcn_global_load_lds((__attribute__((address_space(1))) void*)g,
                                   (__attribute__((address_space(3))) void*)l,
                                   16, 0, 0);
}

// ---------------- fp32 -> bf16 cast (vectorized, n % 2048 == 0) ----------------
__global__ __launch_bounds__(256) void k_cast_bf16(const float* __restrict__ in,
                                                   unsigned short* __restrict__ out, int n) {
  int i = (blockIdx.x * 256 + threadIdx.x) * 8;
  if (i >= n) return;
  float4 a = *reinterpret_cast<const float4*>(in + i);
  float4 b = *reinterpret_cast<const float4*>(in + i + 4);
  u16x8 o;
  o[0] = f2bf(a.x); o[1] = f2bf(a.y); o[2] = f2bf(a.z); o[3] = f2bf(a.w);
  o[4] = f2bf(b.x); o[5] = f2bf(b.y); o[6] = f2bf(b.z); o[7] = f2bf(b.w);
  *reinterpret_cast<u16x8*>(out + i) = o;
}

// ---------------- GEMM C = A * B^T (+bias), A:[M][K] bf16, B:[N][K] bf16 -------
// 128x128 tile, BK=32, 256 threads = 4 waves (2x2), each wave 64x64 via 4x4 MFMA.
template <bool F32OUT>
__global__ __launch_bounds__(256) void k_gemm_bt(const unsigned short* __restrict__ A,
                                                 const unsigned short* __restrict__ Bw,
                                                 unsigned short* __restrict__ Cb,
                                                 float* __restrict__ Cf,
                                                 const float* __restrict__ bias,
                                                 int K, int ldc) {
  __shared__ unsigned short As[128 * 32];
  __shared__ unsigned short Bs[128 * 32];
  const int t = threadIdx.x;
  const int lane = t & 63, w = t >> 6;
  const int wm = w >> 1, wn = w & 1;
  const int g = lane >> 4, r16 = lane & 15;
  const size_t am0 = (size_t)blockIdx.x * 128;
  const size_t bn0 = (size_t)blockIdx.y * 128;

  f32x4 acc[4][4] = {};

  // staging assignment: 2 passes of 256 threads * 16B = 8KB per tile
  const int o0 = t * 16;             // bytes into tile
  const int row0 = o0 >> 6, cb0 = o0 & 63;
  const int o1 = 4096 + t * 16;
  const int row1 = o1 >> 6, cb1 = o1 & 63;

  for (int kb = 0; kb < K; kb += 32) {
    __syncthreads();  // previous iteration's ds_reads complete
    gload_lds16(A  + (am0 + row0) * K + kb + (cb0 >> 1), (char*)As + o0);
    gload_lds16(A  + (am0 + row1) * K + kb + (cb1 >> 1), (char*)As + o1);
    gload_lds16(Bw + (bn0 + row0) * K + kb + (cb0 >> 1), (char*)Bs + o0);
    gload_lds16(Bw + (bn0 + row1) * K + kb + (cb1 >> 1), (char*)Bs + o1);
    __syncthreads();  // emits vmcnt(0)+lgkmcnt(0) drain, LDS ready

    bf16x8 af[4], bfr[4];
#pragma unroll
    for (int i = 0; i < 4; ++i)
      af[i] = *reinterpret_cast<const bf16x8*>((const char*)As + (wm * 64 + i * 16 + r16) * 64 + g * 16);
#pragma unroll
    for (int j = 0; j < 4; ++j)
      bfr[j] = *reinterpret_cast<const bf16x8*>((const char*)Bs + (wn * 64 + j * 16 + r16) * 64 + g * 16);
#pragma unroll
    for (int i = 0; i < 4; ++i)
#pragma unroll
      for (int j = 0; j < 4; ++j)
        acc[i][j] = __builtin_amdgcn_mfma_f32_16x16x32_bf16(af[i], bfr[j], acc[i][j], 0, 0, 0);
  }

  // epilogue: C/D layout col = lane&15, row = (lane>>4)*4 + r
#pragma unroll
  for (int i = 0; i < 4; ++i)
#pragma unroll
    for (int j = 0; j < 4; ++j) {
      size_t row = am0 + wm * 64 + i * 16 + g * 4;
      size_t col = bn0 + wn * 64 + j * 16 + r16;
#pragma unroll
      for (int r = 0; r < 4; ++r) {
        float v = acc[i][j][r];
        if (F32OUT) Cf[(row + r) * ldc + col] = v + bias[col];
        else        Cb[(row + r) * ldc + col] = f2bf(v);
      }
    }
}

// ---------------- per-head RMSNorm + RoPE, in place on qkv ----------------
// grid = B*L blocks, 256 threads; wave = one head (64 lanes = 64 dims)
__global__ __launch_bounds__(256) void k_norm_rope(unsigned short* __restrict__ qkv,
                                                   const float* __restrict__ pe,
                                                   const float* __restrict__ qs,
                                                   const float* __restrict__ ks) {
  const int row = blockIdx.x;          // b*L + l
  const int l = row & (LL - 1);
  const int w = threadIdx.x >> 6, lane = threadIdx.x & 63;
  const size_t base = (size_t)row * 3072;
  const float qsc = qs[lane], ksc = ks[lane];
  // pe[1,1,L,32,2,2]: p = lane>>1, i = lane&1 -> (pe[..,i,0], pe[..,i,1])
  const float2 pe2 = *reinterpret_cast<const float2*>(pe + ((size_t)l * 32 + (lane >> 1)) * 4 + (lane & 1) * 2);

#pragma unroll
  for (int hh = 0; hh < 4; ++hh) {
    const int h = w * 4 + hh;
    unsigned short* qp = qkv + base + h * 64 + lane;
    unsigned short* kp = qkv + base + 1024 + h * 64 + lane;
    float q = bf2f(*qp), k = bf2f(*kp);
    float sq = q * q, sk = k * k;
#pragma unroll
    for (int m = 1; m < 64; m <<= 1) { sq += __shfl_xor(sq, m); sk += __shfl_xor(sk, m); }
    float nq = q * rsqrtf(sq * (1.0f / 64.0f) + 1e-6f) * qsc;
    float nk = k * rsqrtf(sk * (1.0f / 64.0f) + 1e-6f) * ksc;
    // RoPE pair rotation: out = pe[i][0]*x_even + pe[i][1]*x_odd
    float pq = __shfl_xor(nq, 1), pk = __shfl_xor(nk, 1);
    float qe = (lane & 1) ? pq : nq, qo = (lane & 1) ? nq : pq;
    float ke = (lane & 1) ? pk : nk, ko = (lane & 1) ? nk : pk;
    *qp = f2bf(pe2.x * qe + pe2.y * qo);
    *kp = f2bf(pe2.x * ke + pe2.y * ko);
  }
}

// ---------------- flash attention ----------------
// grid = (L/64, B*H), 256 threads = 4 waves; wave w handles q-rows [x*64+w*16, +16)
// K/V read from qkv rows (stride 3072), output ob[b][l][h*64+d] bf16.
__global__ __launch_bounds__(256) void k_flash(const unsigned short* __restrict__ qkv,
                                               unsigned short* __restrict__ ob) {
  __shared__ unsigned short VT[64][40];          // V^T, padded stride 40 (80B, 16B aligned)
  __shared__ unsigned short Pw[4][16][32];       // per-wave P tile
  const int t = threadIdx.x;
  const int w = t >> 6, lane = t & 63;
  const int g = lane >> 4, r16 = lane & 15;
  const int bh = blockIdx.y, b = bh >> 4, h = bh & 15;
  const size_t rowbase = (size_t)b * LL * 3072;
  const int l0 = blockIdx.x * 64 + w * 16;

  // Q fragments (A-operand): row = lane&15, k = (lane>>4)*8+j
  bf16x8 aq[2];
  {
    const unsigned short* qp = qkv + rowbase + (size_t)(l0 + r16) * 3072 + h * 64 + g * 8;
    aq[0] = *reinterpret_cast<const bf16x8*>(qp);
    aq[1] = *reinterpret_cast<const bf16x8*>(qp + 32);
  }

  f32x4 oacc[4] = {};
  float m[4] = {-1e30f, -1e30f, -1e30f, -1e30f};
  float lsum[4] = {0.f, 0.f, 0.f, 0.f};
  const unsigned short* Kbase = qkv + rowbase + 1024 + h * 64;
  const unsigned short* Vbase = qkv + rowbase + 2048 + h * 64;

  for (int kt = 0; kt < LL; kt += 32) {
    __syncthreads();  // all waves done reading previous VT
    // stage V^T cooperatively: thread t -> key = t&31, dims dg*8..dg*8+7
    {
      const int key = t & 31, dg = t >> 5;
      u16x8 vv = *reinterpret_cast<const u16x8*>(Vbase + (size_t)(kt + key) * 3072 + dg * 8);
#pragma unroll
      for (int j = 0; j < 8; ++j) VT[dg * 8 + j][key] = vv[j];
    }
    // S = Q * K^T (K B-fragments direct from global; col = key = lane&15)
    bf16x8 bk[2][2];
#pragma unroll
    for (int s = 0; s < 2; ++s) {
      const unsigned short* kp = Kbase + (size_t)(kt + s * 16 + r16) * 3072 + g * 8;
      bk[s][0] = *reinterpret_cast<const bf16x8*>(kp);
      bk[s][1] = *reinterpret_cast<const bf16x8*>(kp + 32);
    }
    float sv[2][4];
#pragma unroll
    for (int s = 0; s < 2; ++s) {
      f32x4 z = {};
      z = __builtin_amdgcn_mfma_f32_16x16x32_bf16(aq[0], bk[s][0], z, 0, 0, 0);
      z = __builtin_amdgcn_mfma_f32_16x16x32_bf16(aq[1], bk[s][1], z, 0, 0, 0);
#pragma unroll
      for (int r = 0; r < 4; ++r) sv[s][r] = z[r] * 0.125f;  // 1/sqrt(64)
    }
    // row stats over 32 keys: reduce across 16-lane group (cols), rows = g*4+r
    float mx[4], rs[4];
#pragma unroll
    for (int r = 0; r < 4; ++r) mx[r] = fmaxf(sv[0][r], sv[1][r]);
#pragma unroll
    for (int d = 1; d < 16; d <<= 1)
#pragma unroll
      for (int r = 0; r < 4; ++r) mx[r] = fmaxf(mx[r], __shfl_xor(mx[r], d));
    float alpha[4];
#pragma unroll
    for (int r = 0; r < 4; ++r) {
      float mn = fmaxf(m[r], mx[r]);
      alpha[r] = __expf(m[r] - mn);
      m[r] = mn;
      rs[r] = 0.f;
    }
    float p[2][4];
#pragma unroll
    for (int s = 0; s < 2; ++s)
#pragma unroll
      for (int r = 0; r < 4; ++r) { p[s][r] = __expf(sv[s][r] - m[r]); rs[r] += p[s][r]; }
#pragma unroll
    for (int d = 1; d < 16; d <<= 1)
#pragma unroll
      for (int r = 0; r < 4; ++r) rs[r] += __shfl_xor(rs[r], d);
#pragma unroll
    for (int r = 0; r < 4; ++r) lsum[r] = lsum[r] * alpha[r] + rs[r];
#pragma unroll
    for (int dt = 0; dt < 4; ++dt)
#pragma unroll
      for (int r = 0; r < 4; ++r) oacc[dt][r] *= alpha[r];
    // P tile -> per-wave LDS (C layout -> row-major [16][32])
#pragma unroll
    for (int s = 0; s < 2; ++s)
#pragma unroll
      for (int r = 0; r < 4; ++r) Pw[w][g * 4 + r][s * 16 + r16] = f2bf(p[s][r]);
    __syncthreads();  // VT writes visible to all waves
    // O += P * V : A = P (row=lane&15, k=g*8+j), B = VT (col=dim=lane&15, k=key)
    bf16x8 ap = *reinterpret_cast<const bf16x8*>((const char*)Pw[w] + r16 * 64 + g * 16);
#pragma unroll
    for (int dt = 0; dt < 4; ++dt) {
      bf16x8 bv = *reinterpret_cast<const bf16x8*>((const char*)VT + (dt * 16 + r16) * 80 + g * 16);
      oacc[dt] = __builtin_amdgcn_mfma_f32_16x16x32_bf16(ap, bv, oacc[dt], 0, 0, 0);
    }
  }

  // epilogue: normalize and store to ob[b][l][h*64+d]
  float inv[4];
#pragma unroll
  for (int r = 0; r < 4; ++r) inv[r] = 1.0f / lsum[r];
  const size_t ob_base = (size_t)b * LL * 1024 + h * 64;
#pragma unroll
  for (int dt = 0; dt < 4; ++dt)
#pragma unroll
    for (int r = 0; r < 4; ++r)
      ob[ob_base + (size_t)(l0 + g * 4 + r) * 1024 + dt * 16 + r16] = f2bf(oacc[dt][r] * inv[r]);
}

// ---------------- launch ----------------
extern "C" void kernel_launch(void* const* d_in, const int* in_sizes, int n_in,
                              void* d_out, int out_size, void* d_ws, size_t ws_size,
                              hipStream_t stream) {
  const float* x     = (const float*)d_in[0];
  const float* pe    = (const float*)d_in[1];
  const float* Wq    = (const float*)d_in[2];
  const float* Wkv   = (const float*)d_in[3];
  const float* Wproj = (const float*)d_in[4];
  const float* bproj = (const float*)d_in[5];
  const float* qs    = (const float*)d_in[6];
  const float* ks    = (const float*)d_in[7];
  float* out = (float*)d_out;

  // workspace layout (48MB total)
  char* ws = (char*)d_ws;
  unsigned short* xb     = (unsigned short*)(ws);                        // x bf16      8MB
  unsigned short* Wqb    = (unsigned short*)(ws + 8u  * 1024 * 1024);    // Wq bf16     2MB
  unsigned short* Wkvb   = (unsigned short*)(ws + 10u * 1024 * 1024);    // Wkv bf16    4MB
  unsigned short* Wprojb = (unsigned short*)(ws + 14u * 1024 * 1024);    // Wproj bf16  2MB
  unsigned short* qkv    = (unsigned short*)(ws + 16u * 1024 * 1024);    // [4096][3072] 24MB
  unsigned short* ob     = (unsigned short*)(ws + 40u * 1024 * 1024);    // [4096][1024] 8MB

  k_cast_bf16<<<4194304 / 2048, 256, 0, stream>>>(x, xb, 4194304);
  k_cast_bf16<<<1048576 / 2048, 256, 0, stream>>>(Wq, Wqb, 1048576);
  k_cast_bf16<<<2097152 / 2048, 256, 0, stream>>>(Wkv, Wkvb, 2097152);
  k_cast_bf16<<<1048576 / 2048, 256, 0, stream>>>(Wproj, Wprojb, 1048576);

  // q -> qkv cols [0,1024), k|v -> qkv cols [1024,3072)
  k_gemm_bt<false><<<dim3(32, 8),  256, 0, stream>>>(xb, Wqb,  qkv,        nullptr, nullptr, 1024, 3072);
  k_gemm_bt<false><<<dim3(32, 16), 256, 0, stream>>>(xb, Wkvb, qkv + 1024, nullptr, nullptr, 1024, 3072);

  k_norm_rope<<<BB * LL, 256, 0, stream>>>(qkv, pe, qs, ks);
  k_flash<<<dim3(LL / 64, BB * NH), 256, 0, stream>>>(qkv, ob);

  k_gemm_bt<true><<<dim3(32, 8), 256, 0, stream>>>(ob, Wprojb, nullptr, out, bproj, 1024, 1024);
}